// Round 14
// baseline (183.438 us; speedup 1.0000x reference)
//
#include <hip/hip_runtime.h>
#include <stdint.h>

typedef __attribute__((ext_vector_type(8))) short bf16x8;
typedef __attribute__((ext_vector_type(4))) float f32x4;
typedef __attribute__((ext_vector_type(4))) unsigned short u16x4;
typedef __attribute__((ext_vector_type(4))) unsigned int u32x4;

#define NB 32
#define HH 128
#define WW 128
#define CI 128
#define CO 128
#define HO 126
#define WO 126
#define DTH 32             // double-tile h
#define TW 16
#define PH2 34             // patch h = DTH + 2
#define PWw 18             // patch w = TW + 2
#define NR2 (PH2 * PWw)    // 612 patch rows
#define QSH (NR2 * 32)     // 19584 shorts = 39168 B per ci-quarter buffer
#define NSLOT (NR2 * 4)    // 2448 16B-granules per quarter

__device__ __forceinline__ unsigned short f2bf(float f) {
  union { float f; unsigned u; } x; x.f = f;
  unsigned u = x.u;
  u += 0x7FFFu + ((u >> 16) & 1u);   // RNE round to bf16
  return (unsigned short)(u >> 16);
}

// cvt_pk_bf16_f32: RNE, packs 2 f32 -> 2 bf16 in one VALU op (no builtin on gfx950)
__device__ __forceinline__ unsigned cvtpk_bf16(float a, float b) {
  unsigned r;
  asm("v_cvt_pk_bf16_f32 %0, %1, %2" : "=v"(r) : "v"(a), "v"(b));
  return r;  // low16 = bf16(a), high16 = bf16(b)
}

// prep: [b,p][ci][co] f32 -> fragment-blocked bf16, slice-major [b][ch][p][kc]:
//   slice = (ch*9+p)*2+kc (4096 shorts each); within: f*512 + lane*8 + e
//   holds kin[b,p][ci = ch*64+kc*32+(lane>>4)*8+e][co = (f>>2)*64+(f&3)*16+(lane&15)]
__global__ void prep_kt(const float* __restrict__ kin, unsigned short* __restrict__ ktr) {
  __shared__ unsigned short t[CI * CO];  // 32 KB
  int bp = blockIdx.x;  // b*9+p, 0..287
  int b = bp / 9, p = bp % 9;
  const float* src = kin + (size_t)bp * (CI * CO);
  unsigned short* dstb = ktr + (size_t)b * (9 * CI * CO);
  for (int i = threadIdx.x; i < CI * CO / 4; i += blockDim.x) {
    f32x4 v = *(const f32x4*)(src + i * 4);
    u16x4 o;
    o.x = f2bf(v.x); o.y = f2bf(v.y); o.z = f2bf(v.z); o.w = f2bf(v.w);
    *(u16x4*)&t[i * 4] = o;
  }
  __syncthreads();
  for (int j = threadIdx.x; j < 2048; j += blockDim.x) {  // j = (sl*8+f)*64+lane
    int lane = j & 63, f = (j >> 6) & 7, sl = j >> 9;     // sl = ch*2+kc
    int ch = sl >> 1, kc = sl & 1;
    int co = (f >> 2) * 64 + (f & 3) * 16 + (lane & 15);
    int ci0 = ch * 64 + kc * 32 + (lane >> 4) * 8;
    bf16x8 v;
#pragma unroll
    for (int e = 0; e < 8; ++e) v[e] = t[(ci0 + e) * CO + co];
    int slice = (ch * 9 + p) * 2 + kc;
    *(bf16x8*)&dstb[(size_t)slice * 4096 + f * 512 + lane * 8] = v;
  }
}

// naive fallback (only if ws_size too small — not expected on this harness)
__global__ void conv_naive(const float* __restrict__ X, const float* __restrict__ Kf,
                           float* __restrict__ out) {
  int idx = blockIdx.x * blockDim.x + threadIdx.x;           // over B*HO*WO*CO
  if (idx >= NB * HO * WO * CO) return;
  int co = idx & 127, t = idx >> 7;
  int wp = t % WO; t /= WO;
  int hp = t % HO; int b = t / HO;
  const float* xb = X + (size_t)b * HH * WW * CI;
  const float* kb = Kf + (size_t)b * 9 * CI * CO;
  float s = 0.f;
  for (int p = 0; p < 9; ++p) {
    int kh = p / 3, kw = p % 3;
    const float* xr = xb + ((size_t)(hp + kh) * WW + (wp + kw)) * CI;
    const float* kr = kb + (size_t)p * CI * CO + co;
    for (int ci = 0; ci < CI; ++ci) s += xr[ci] * kr[(size_t)ci * CO];
  }
  out[idx] = s;
}

// Persistent 1-block/CU, 512 thr = 2 waves/SIMD, ~256 regs/thread. R14 core
// change: acc DOUBLED to 128 regs (wave slab m8 x n4 = 8h x 16w x 64co).
// Per cluster a wave runs 32 MFMAs on 12 KB operands (was 16 on 10 KB):
// per-CU operand feed drops to A 64KB(LDS) + B 32KB(TCP) per 1024 cyc of
// per-SIMD MFMA — both feed pipes now fit UNDER the matrix pipe (R13's
// measured 1450cyc round was feed-bound: LDS 768 + TCP 256 vs MFMA 512).
// Double-tile 32h x 16w x 128co; ci-quarter linear-64B LDS (R7-proven
// pattern) ping-pong; 9 p-clusters per quarter-pass; 16 passes.
__global__ __launch_bounds__(512, 2) void conv_main(
    const float* __restrict__ X, const unsigned short* __restrict__ Kt,
    float* __restrict__ out) {
  __shared__ unsigned short lds_q[2][QSH];   // 2 x 39168 B = 78336 B

  const int tid = threadIdx.x;
  const int lane = tid & 63;
  const int wid = tid >> 6;            // 8 waves, 4 (h) x 2 (co)
  const int wr = wid >> 1, wc = wid & 1;
  const int ks = lane >> 4, lr = lane & 15;

  // block -> (xcd, batch, w-column); h swept as 4 double-tiles
  const int bx = blockIdx.x;           // 0..255
  const int xcd = bx & 7, v = bx >> 3; // v: 0..31
  const int b = xcd * 4 + (v >> 3);    // 4 batches per XCD (L2-resident B)
  const int wt = v & 7;
  const int w0 = wt * TW;

  const float* xb = X + (size_t)b * HH * WW * CI;

  // ---- stage geometry: granule k (k=0..4) = slot tid+512k; row=(tid>>2)+128k,
  // g=tid&3 (16B chunk = 8 ci of the 32-ci quarter). Linear rows: dst byte =
  // row*64 + g*16 (+k*8192) — contiguous per wave, conflict-free b128 writes.
  const int g4 = tid & 3;
  const int a0 = tid >> 2;             // 0..127
  int hI[5]; unsigned baseI[5]; unsigned okm = 0;
#pragma unroll
  for (int k = 0; k < 5; ++k) {
    int row = a0 + 128 * k;            // <= 639; live slots need row < 612
    int h = row / PWw, w = row - PWw * h;
    int gw = w0 + w;
    if ((row < NR2) && (gw < WW)) okm |= (1u << k);
    hI[k] = h;
    baseI[k] = (unsigned)((h * WW + (gw & 127)) * CI + g4 * 8);  // f32 elems
  }
  const int dst0 = a0 * 32 + g4 * 8;   // shorts; granule k adds k*4096

  auto sIssue = [&](int k, int h0n, int qn, f32x4& ga, f32x4& gb) {
    bool ok = ((okm >> k) & 1) && (h0n + hI[k] < HH);
    const float* sp = xb + (ok ? baseI[k] + (unsigned)(h0n << 14) + (unsigned)(qn << 5)
                               : (unsigned)(g4 * 8));
    ga = *(const f32x4*)sp;
    gb = *(const f32x4*)(sp + 4);
  };
  auto sWrite = [&](int k, int h0n, unsigned short* wbuf, const f32x4& ga, const f32x4& gb) {
    bool live = (k < 4) | (tid < (NSLOT - 2048));   // k=4: tid<400
    if (!live) return;
    bool ok = ((okm >> k) & 1) && (h0n + hI[k] < HH);
    u32x4 o;
    o.x = ok ? cvtpk_bf16(ga.x, ga.y) : 0u;
    o.y = ok ? cvtpk_bf16(ga.z, ga.w) : 0u;
    o.z = ok ? cvtpk_bf16(gb.x, gb.y) : 0u;
    o.w = ok ? cvtpk_bf16(gb.z, gb.w) : 0u;
    *(u32x4*)&wbuf[dst0 + k * 4096] = o;
  };

  // ---- compute: af byte = aoff + ((m+kh)*18 + kw)*64 (imm); max 39152 ----
  const int aoff = ((wr * 8) * PWw + lr) * 64 + ks * 16;

  // B: wave wc's 4 co-frags (64 co) = 4 contiguous 1KB bursts per slice.
  const unsigned short* ktw = Kt + (size_t)b * 9 * CI * CO + (wc * 4) * 512 + lane * 8;
  bf16x8 Hf[2][4];                     // ring-2, distance-1 (depth-2 was null, R12)
  auto loadB = [&](bf16x8 (&dst)[4], const unsigned short* p) {
#pragma unroll
    for (int n = 0; n < 4; ++n)
      dst[n] = *(const bf16x8*)(p + n * 512);
  };

  f32x4 zero = {0.f, 0.f, 0.f, 0.f};
  f32x4 acc[8][4];                     // 128 VGPRs
#pragma unroll
  for (int m = 0; m < 8; ++m)
#pragma unroll
    for (int n = 0; n < 4; ++n) acc[m][n] = zero;

  float* const ob = out + (size_t)b * HO * WO * CO;

  // ---- prologue: stage pass-0 (dt0, q0) into buf0; prefetch B(q0,p0) ----
  {
    f32x4 ga, gb;
#pragma unroll
    for (int k = 0; k < 5; ++k) {
      sIssue(k, 0, 0, ga, gb);
      sWrite(k, 0, &lds_q[0][0], ga, gb);
    }
  }
  loadB(Hf[0], ktw);
  __syncthreads();

  f32x4 gAa, gAb, gBa, gBb;            // 2 stage granules in flight (16 regs)

#pragma unroll 1
  for (int k = 0; k < 16; ++k) {       // 16 passes = 4 double-tiles x 4 quarters
    const int q = k & 3;
    const int h0 = (k >> 2) * DTH;
    const char* rb = (const char*)&lds_q[k & 1][0];
    unsigned short* wbuf = &lds_q[(k + 1) & 1][0];
    const unsigned short* bq = ktw + (size_t)((q >> 1) * 18 + (q & 1)) * 4096;
    const bool stg = (k < 15);
    const int qn = (k + 1) & 3;
    const int h0n = ((k + 1) >> 2) * DTH;
    const unsigned short* bqn = ktw + (size_t)((qn >> 1) * 18 + (qn & 1)) * 4096;

#pragma unroll
    for (int s = 0; s < 9; ++s) {      // p = s; all indices compile-time
      const int kh = s / 3, kw = s % 3;
      // B prefetch distance-1 (cross-pass load moved AFTER mma, keeps parity static)
      if (s < 8) loadB(Hf[(s + 1) & 1], bq + (size_t)(s + 1) * 8192);
      // stage: writes (2-cluster gap) then issues — ring of 2 granules
      if (stg) {
        if (s == 2) sWrite(0, h0n, wbuf, gAa, gAb);
        if (s == 3) sWrite(1, h0n, wbuf, gBa, gBb);
        if (s == 4) sWrite(2, h0n, wbuf, gAa, gAb);
        if (s == 5) sWrite(3, h0n, wbuf, gBa, gBb);
        if (s == 6) sWrite(4, h0n, wbuf, gAa, gAb);
        if (s == 0) sIssue(0, h0n, qn, gAa, gAb);
        if (s == 1) sIssue(1, h0n, qn, gBa, gBb);
        if (s == 2) sIssue(2, h0n, qn, gAa, gAb);
        if (s == 3) sIssue(3, h0n, qn, gBa, gBb);
        if (s == 4) sIssue(4, h0n, qn, gAa, gAb);
      }
      // af low half + 16 MFMA, then high half + 16 MFMA
      {
        bf16x8 af[4];
#pragma unroll
        for (int m = 0; m < 4; ++m)
          af[m] = *(const bf16x8*)(rb + aoff + ((m + kh) * PWw + kw) * 64);
        __builtin_amdgcn_s_setprio(1);
#pragma unroll
        for (int m = 0; m < 4; ++m)
#pragma unroll
          for (int n = 0; n < 4; ++n)
            acc[m][n] = __builtin_amdgcn_mfma_f32_16x16x32_bf16(af[m], Hf[s & 1][n],
                                                                acc[m][n], 0, 0, 0);
        __builtin_amdgcn_s_setprio(0);
#pragma unroll
        for (int m = 0; m < 4; ++m)
          af[m] = *(const bf16x8*)(rb + aoff + ((m + 4 + kh) * PWw + kw) * 64);
        __builtin_amdgcn_s_setprio(1);
#pragma unroll
        for (int m = 0; m < 4; ++m)
#pragma unroll
          for (int n = 0; n < 4; ++n)
            acc[m + 4][n] = __builtin_amdgcn_mfma_f32_16x16x32_bf16(af[m], Hf[s & 1][n],
                                                                    acc[m + 4][n], 0, 0, 0);
        __builtin_amdgcn_s_setprio(0);
      }
      if (s == 8 && stg) loadB(Hf[0], bqn);   // WAR-safe: s=8 MFMAs issued
    }

    if (q == 3) {                      // double-tile done: epilogue + reset
#pragma unroll
      for (int m = 0; m < 8; ++m) {
        int hp = h0 + wr * 8 + m;
        if (hp >= HO) continue;
#pragma unroll
        for (int r = 0; r < 4; ++r) {
          int wp = w0 + ks * 4 + r;
          if (wp >= WO) continue;
#pragma unroll
          for (int n = 0; n < 4; ++n) {
            int co = wc * 64 + n * 16 + lr;
            ob[((size_t)hp * WO + wp) * CO + co] = acc[m][n][r];
          }
        }
      }
#pragma unroll
      for (int m = 0; m < 8; ++m)
#pragma unroll
        for (int n = 0; n < 4; ++n) acc[m][n] = zero;
    }
    if (k < 15) __syncthreads();       // stage(k+1) visible; WAR on rb safe
  }
}

extern "C" void kernel_launch(void* const* d_in, const int* in_sizes, int n_in,
                              void* d_out, int out_size, void* d_ws, size_t ws_size,
                              hipStream_t stream) {
  const float* X = (const float*)d_in[0];
  const float* Kf = (const float*)d_in[1];
  float* out = (float*)d_out;
  size_t need = (size_t)NB * 9 * CI * CO * sizeof(unsigned short);  // 9.4 MB
  if (d_ws != nullptr && ws_size >= need) {
    unsigned short* ktr = (unsigned short*)d_ws;
    prep_kt<<<dim3(NB * 9), 256, 0, stream>>>(Kf, ktr);
    conv_main<<<dim3(256), 512, 0, stream>>>(X, ktr, out);
  } else {
    int total = NB * HO * WO * CO;
    conv_naive<<<(total + 255) / 256, 256, 0, stream>>>(X, Kf, out);
  }
}